// Round 3
// baseline (152.768 us; speedup 1.0000x reference)
//
#include <hip/hip_runtime.h>
#include <math.h>

namespace {

constexpr int SOUT = 12;    // (14-3)/1+1
constexpr int OCAP = 32;
constexpr int PD   = 16;    // 4x4 pose
constexpr int NI   = 288;   // 3*3*32
constexpr int NPOS = 4 * SOUT * SOUT;  // 576
constexpr float EPSF = 1e-9f;
constexpr size_t POSE_OUT = (size_t)NPOS * OCAP * PD;  // 294912

// One block per output position. 512 threads = 8 waves.
// lane -> (o = lane&31, half = lane>>5); per step a wave handles 2 input caps.
__global__ __launch_bounds__(512, 6)
void caps_em_fused(const float* __restrict__ pose_in,   // [4,14,14,32,16]
                   const float* __restrict__ act_in,    // [4,14,14,32]
                   const float* __restrict__ wmat,      // [288,32,16]
                   const float* __restrict__ beta_v,    // [32]
                   const float* __restrict__ beta_a,    // [32]
                   float* __restrict__ out)             // pose ++ act
{
    __shared__ __align__(16) float sP[NI * PD];   // 18 KB patch poses
    __shared__ float sA[NI];                      // patch activations
    __shared__ float sInv2[OCAP][PD + 1];         // 1/(2*var)
    __shared__ float sNeg[OCAP][PD + 1];          // -2*mean/(2*var)
    __shared__ float sBias[OCAP];                 // log(oact+EPS) - lt - C0
    __shared__ float sRed[4][33][33];             // two-round cross-wave partials

    const int n  = blockIdx.x;
    const int b  = n / (SOUT * SOUT);
    const int yx = n % (SOUT * SOUT);
    const int y  = yx / SOUT;
    const int x  = yx % SOUT;

    const int t    = threadIdx.x;
    const int wave = t >> 6;            // 0..7
    const int lane = t & 63;
    const int o    = lane & 31;
    const int half = lane >> 5;

    // ---- stage 3x3 patch into LDS (coalesced float4) ----
    {
        const float4* src = reinterpret_cast<const float4*>(pose_in);
        float4* dst = reinterpret_cast<float4*>(sP);
        for (int u = t; u < NI * 4; u += 512) {   // 1152 float4
            const int k = u >> 7, idx = u & 127;  // cell, float4-within-cell
            const int ki = k / 3, kj = k - ki * 3;
            const int cell = (b * 14 + y + ki) * 14 + (x + kj);
            dst[u] = src[(size_t)cell * 128 + idx];
        }
        for (int u = t; u < NI; u += 512) {
            const int k = u >> 5, c = u & 31;
            const int ki = k / 3, kj = k - ki * 3;
            const int cell = (b * 14 + y + ki) * 14 + (x + kj);
            sA[u] = act_in[(size_t)cell * 32 + c];
        }
    }
    __syncthreads();

    for (int sweep = 0; sweep < 3; ++sweep) {
        const float bias_r = (sweep > 0) ? sBias[o] : 0.f;

        float s1[PD], s2[PD];
        float s0 = 0.f;
        #pragma unroll
        for (int d = 0; d < PD; ++d) { s1[d] = 0.f; s2[d] = 0.f; }

        #pragma unroll 1
        for (int step = 0; step < NI / 16; ++step) {   // 18 steps
            const int i = step * 16 + wave * 2 + half;

            float P[PD], W[PD];
            const float* pr = &sP[i * PD];
            #pragma unroll
            for (int q4 = 0; q4 < 4; ++q4) {           // LDS broadcast
                const float4 pv = *reinterpret_cast<const float4*>(&pr[q4 * 4]);
                P[q4*4+0] = pv.x; P[q4*4+1] = pv.y; P[q4*4+2] = pv.z; P[q4*4+3] = pv.w;
            }
            const float* wr = wmat + ((size_t)i * OCAP + o) * PD;
            #pragma unroll
            for (int q4 = 0; q4 < 4; ++q4) {           // half-wave reads 2KB contiguous (L2)
                const float4 wv = *reinterpret_cast<const float4*>(&wr[q4 * 4]);
                W[q4*4+0] = wv.x; W[q4*4+1] = wv.y; W[q4*4+2] = wv.z; W[q4*4+3] = wv.w;
            }

            // votes[p,r] = sum_q P[p,q] * W[q,r]
            float v[PD];
            #pragma unroll
            for (int p = 0; p < 4; ++p) {
                #pragma unroll
                for (int r = 0; r < 4; ++r) {
                    float acc = P[p*4+0] * W[r];
                    acc = fmaf(P[p*4+1], W[4  + r], acc);
                    acc = fmaf(P[p*4+2], W[8  + r], acc);
                    acc = fmaf(P[p*4+3], W[12 + r], acc);
                    v[p*4+r] = acc;
                }
            }

            const float a_i = sA[i];
            float rrp;
            if (sweep == 0) {
                rrp = a_i * (1.0f / 32.0f);            // uniform rr = 1/O
            } else {
                // ts = sum_d (v-m)^2/(2var) expanded: v*(v*inv2 - 2*m*inv2), C0 in bias
                float ts = 0.f;
                #pragma unroll
                for (int d = 0; d < PD; ++d) {
                    const float h = fmaf(v[d], sInv2[o][d], sNeg[o][d]);
                    ts = fmaf(v[d], h, ts);
                }
                float zz = bias_r - ts;
                float m = zz;
                #pragma unroll
                for (int msk = 16; msk >= 1; msk >>= 1)
                    m = fmaxf(m, __shfl_xor(m, msk, 32));
                const float e = __expf(zz - m);
                float es = e;
                #pragma unroll
                for (int msk = 16; msk >= 1; msk >>= 1)
                    es += __shfl_xor(es, msk, 32);
                rrp = __fdividef(e, es) * a_i;         // rr * i_act
            }

            s0 += rrp;
            #pragma unroll
            for (int d = 0; d < PD; ++d) {
                const float rv = rrp * v[d];
                s1[d] = fmaf(rrp, v[d], s1[d]);
                s2[d] = fmaf(rv, v[d], s2[d]);
            }
        }

        // fold the two halves (same o) within each wave
        #pragma unroll
        for (int d = 0; d < PD; ++d) {
            s1[d] += __shfl_xor(s1[d], 32, 64);
            s2[d] += __shfl_xor(s2[d], 32, 64);
        }
        s0 += __shfl_xor(s0, 32, 64);

        // two-round cross-wave reduction into sRed[4][33][33]
        if (wave < 4 && half == 0) {
            #pragma unroll
            for (int d = 0; d < PD; ++d) {
                sRed[wave][d][o]      = s1[d];
                sRed[wave][16 + d][o] = s2[d];
            }
            sRed[wave][32][o] = s0;
        }
        __syncthreads();
        if (wave >= 4 && half == 0) {
            #pragma unroll
            for (int d = 0; d < PD; ++d) {
                sRed[wave - 4][d][o]      += s1[d];
                sRed[wave - 4][16 + d][o] += s2[d];
            }
            sRed[wave - 4][32][o] += s0;
        }
        __syncthreads();

        // ---- M-step on waves 0-3: thread = (o, d-pair) ----
        if (t < 256) {
            const int oo = t >> 3, dp = t & 7, d0 = dp * 2;
            float S0 = 0.f, S1a = 0.f, S1b = 0.f, S2a = 0.f, S2b = 0.f;
            #pragma unroll
            for (int r = 0; r < 4; ++r) {
                S0  += sRed[r][32][oo];
                S1a += sRed[r][d0][oo];
                S1b += sRed[r][d0 + 1][oo];
                S2a += sRed[r][16 + d0][oo];
                S2b += sRed[r][17 + d0][oo];
            }
            const float inv = 1.f / S0;
            const float m0 = S1a * inv, m1 = S1b * inv;
            const float v0 = fmaxf(fmaf(-m0, m0, S2a * inv), 0.f);
            const float v1 = fmaxf(fmaf(-m1, m1, S2b * inv), 0.f);
            if (sweep == 2) {
                float2 pv; pv.x = m0; pv.y = m1;
                *reinterpret_cast<float2*>(out + (size_t)n * (OCAP * PD) + oo * PD + d0) = pv;
            }
            const float i20 = 0.5f / fmaxf(v0, 1e-30f);
            const float i21 = 0.5f / fmaxf(v1, 1e-30f);
            float llocal = __logf(sqrtf(v0) + EPSF) + __logf(sqrtf(v1) + EPSF);
            float c0l    = m0 * m0 * i20 + m1 * m1 * i21;
            if (sweep < 2) {
                sInv2[oo][d0]     = i20;
                sInv2[oo][d0 + 1] = i21;
                sNeg[oo][d0]      = -2.f * m0 * i20;
                sNeg[oo][d0 + 1]  = -2.f * m1 * i21;
            }
            // 8-lane reductions over d-pairs
            #pragma unroll
            for (int msk = 1; msk <= 4; msk <<= 1) {
                llocal += __shfl_xor(llocal, msk, 8);
                c0l    += __shfl_xor(c0l,    msk, 8);
            }
            if (dp == 0) {
                const float lt   = llocal;
                const float cost = S0 * fmaf(16.f, beta_v[oo], lt);
                const float invtemp = 1.0f + (float)sweep;       // 1,2,3
                const float oact = 1.f / (1.f + __expf(-invtemp * (beta_a[oo] - cost)));
                if (sweep < 2)
                    sBias[oo] = __logf(oact + EPSF) - lt - c0l;
                else
                    out[POSE_OUT + (size_t)n * OCAP + oo] = oact;
            }
        }
        __syncthreads();
    }
}

} // namespace

extern "C" void kernel_launch(void* const* d_in, const int* in_sizes, int n_in,
                              void* d_out, int out_size, void* d_ws, size_t ws_size,
                              hipStream_t stream) {
    const float* pose_in = (const float*)d_in[0];
    const float* act_in  = (const float*)d_in[1];
    const float* wmat    = (const float*)d_in[2];
    const float* beta_v  = (const float*)d_in[3];
    const float* beta_a  = (const float*)d_in[4];
    float* out = (float*)d_out;

    caps_em_fused<<<dim3(NPOS), dim3(512), 0, stream>>>(
        pose_in, act_in, wmat, beta_v, beta_a, out);
}

// Round 4
// 133.045 us; speedup vs baseline: 1.1482x; 1.1482x over previous
//
#include <hip/hip_runtime.h>
#include <math.h>

namespace {

constexpr int SOUT = 12;    // (14-3)/1+1
constexpr int OCAP = 32;
constexpr int PD   = 16;    // 4x4 pose
constexpr int NI   = 288;   // 3*3*32
constexpr int NPOS = 4 * SOUT * SOUT;  // 576
constexpr float EPSF = 1e-9f;
constexpr size_t POSE_OUT = (size_t)NPOS * OCAP * PD;  // 294912

// One block per output position. 512 threads = 8 waves.
// lane -> (o = lane&31, half = lane>>5); per step a wave handles 2 input caps.
__global__ __launch_bounds__(512, 4)
void caps_em_fused(const float* __restrict__ pose_in,   // [4,14,14,32,16]
                   const float* __restrict__ act_in,    // [4,14,14,32]
                   const float* __restrict__ wmat,      // [288,32,16]
                   const float* __restrict__ beta_v,    // [32]
                   const float* __restrict__ beta_a,    // [32]
                   float* __restrict__ out)             // pose ++ act
{
    __shared__ __align__(16) float sP[NI * PD];   // 18 KB patch poses
    __shared__ float sA[NI];                      // patch activations
    __shared__ float sInv2[OCAP][PD + 1];         // 1/(2*var)
    __shared__ float sNeg[OCAP][PD + 1];          // -2*mean/(2*var)
    __shared__ float sBias[OCAP];                 // log(oact+EPS) - lt - C0
    __shared__ float sRed[4][33][33];             // two-round cross-wave partials

    const int n  = blockIdx.x;
    const int b  = n / (SOUT * SOUT);
    const int yx = n % (SOUT * SOUT);
    const int y  = yx / SOUT;
    const int x  = yx % SOUT;

    const int t    = threadIdx.x;
    const int wave = t >> 6;            // 0..7
    const int lane = t & 63;
    const int o    = lane & 31;
    const int half = lane >> 5;

    // ---- stage 3x3 patch into LDS (coalesced float4) ----
    {
        const float4* src = reinterpret_cast<const float4*>(pose_in);
        float4* dst = reinterpret_cast<float4*>(sP);
        for (int u = t; u < NI * 4; u += 512) {   // 1152 float4
            const int k = u >> 7, idx = u & 127;  // cell, float4-within-cell
            const int ki = k / 3, kj = k - ki * 3;
            const int cell = (b * 14 + y + ki) * 14 + (x + kj);
            dst[u] = src[(size_t)cell * 128 + idx];
        }
        for (int u = t; u < NI; u += 512) {
            const int k = u >> 5, c = u & 31;
            const int ki = k / 3, kj = k - ki * 3;
            const int cell = (b * 14 + y + ki) * 14 + (x + kj);
            sA[u] = act_in[(size_t)cell * 32 + c];
        }
    }
    __syncthreads();

    for (int sweep = 0; sweep < 3; ++sweep) {
        const float bias_r = (sweep > 0) ? sBias[o] : 0.f;

        float s1[PD], s2[PD];
        float s0 = 0.f;
        #pragma unroll
        for (int d = 0; d < PD; ++d) { s1[d] = 0.f; s2[d] = 0.f; }

        #pragma unroll 1
        for (int step = 0; step < NI / 16; ++step) {   // 18 steps
            const int i = step * 16 + wave * 2 + half;

            // W first (long-latency L2 read: half-wave reads 2KB contiguous)
            float W[PD];
            const float* wr = wmat + ((size_t)i * OCAP + o) * PD;
            #pragma unroll
            for (int q4 = 0; q4 < 4; ++q4) {
                const float4 wv = *reinterpret_cast<const float4*>(&wr[q4 * 4]);
                W[q4*4+0] = wv.x; W[q4*4+1] = wv.y; W[q4*4+2] = wv.z; W[q4*4+3] = wv.w;
            }

            // votes[p,r] = sum_q P[p,q] * W[q,r]; P loaded row-wise (LDS broadcast)
            float v[PD];
            const float* pr = &sP[i * PD];
            #pragma unroll
            for (int p = 0; p < 4; ++p) {
                const float4 pv = *reinterpret_cast<const float4*>(&pr[p * 4]);
                #pragma unroll
                for (int r = 0; r < 4; ++r) {
                    float acc = pv.x * W[r];
                    acc = fmaf(pv.y, W[4  + r], acc);
                    acc = fmaf(pv.z, W[8  + r], acc);
                    acc = fmaf(pv.w, W[12 + r], acc);
                    v[p*4+r] = acc;
                }
            }

            const float a_i = sA[i];
            float rrp;
            if (sweep == 0) {
                rrp = a_i * (1.0f / 32.0f);            // uniform rr = 1/O
            } else {
                // ts = sum_d (v-m)^2/(2var) expanded: v*(v*inv2 - 2*m*inv2), C0 in bias
                float ts = 0.f;
                #pragma unroll
                for (int d = 0; d < PD; ++d) {
                    const float h = fmaf(v[d], sInv2[o][d], sNeg[o][d]);
                    ts = fmaf(v[d], h, ts);
                }
                float zz = bias_r - ts;
                float m = zz;
                #pragma unroll
                for (int msk = 16; msk >= 1; msk >>= 1)
                    m = fmaxf(m, __shfl_xor(m, msk, 32));
                const float e = __expf(zz - m);
                float es = e;
                #pragma unroll
                for (int msk = 16; msk >= 1; msk >>= 1)
                    es += __shfl_xor(es, msk, 32);
                rrp = __fdividef(e, es) * a_i;         // rr * i_act
            }

            s0 += rrp;
            #pragma unroll
            for (int d = 0; d < PD; ++d) {
                const float rv = rrp * v[d];
                s1[d] = fmaf(rrp, v[d], s1[d]);
                s2[d] = fmaf(rv, v[d], s2[d]);
            }
        }

        // fold the two halves (same o) within each wave
        #pragma unroll
        for (int d = 0; d < PD; ++d) {
            s1[d] += __shfl_xor(s1[d], 32, 64);
            s2[d] += __shfl_xor(s2[d], 32, 64);
        }
        s0 += __shfl_xor(s0, 32, 64);

        // two-round cross-wave reduction into sRed[4][33][33]
        if (wave < 4 && half == 0) {
            #pragma unroll
            for (int d = 0; d < PD; ++d) {
                sRed[wave][d][o]      = s1[d];
                sRed[wave][16 + d][o] = s2[d];
            }
            sRed[wave][32][o] = s0;
        }
        __syncthreads();
        if (wave >= 4 && half == 0) {
            #pragma unroll
            for (int d = 0; d < PD; ++d) {
                sRed[wave - 4][d][o]      += s1[d];
                sRed[wave - 4][16 + d][o] += s2[d];
            }
            sRed[wave - 4][32][o] += s0;
        }
        __syncthreads();

        // ---- M-step on waves 0-3: thread = (o, d-pair) ----
        if (t < 256) {
            const int oo = t >> 3, dp = t & 7, d0 = dp * 2;
            float S0 = 0.f, S1a = 0.f, S1b = 0.f, S2a = 0.f, S2b = 0.f;
            #pragma unroll
            for (int r = 0; r < 4; ++r) {
                S0  += sRed[r][32][oo];
                S1a += sRed[r][d0][oo];
                S1b += sRed[r][d0 + 1][oo];
                S2a += sRed[r][16 + d0][oo];
                S2b += sRed[r][17 + d0][oo];
            }
            const float inv = 1.f / S0;
            const float m0 = S1a * inv, m1 = S1b * inv;
            const float v0 = fmaxf(fmaf(-m0, m0, S2a * inv), 0.f);
            const float v1 = fmaxf(fmaf(-m1, m1, S2b * inv), 0.f);
            if (sweep == 2) {
                float2 pv; pv.x = m0; pv.y = m1;
                *reinterpret_cast<float2*>(out + (size_t)n * (OCAP * PD) + oo * PD + d0) = pv;
            }
            const float i20 = 0.5f / fmaxf(v0, 1e-30f);
            const float i21 = 0.5f / fmaxf(v1, 1e-30f);
            float llocal = __logf(sqrtf(v0) + EPSF) + __logf(sqrtf(v1) + EPSF);
            float c0l    = m0 * m0 * i20 + m1 * m1 * i21;
            if (sweep < 2) {
                sInv2[oo][d0]     = i20;
                sInv2[oo][d0 + 1] = i21;
                sNeg[oo][d0]      = -2.f * m0 * i20;
                sNeg[oo][d0 + 1]  = -2.f * m1 * i21;
            }
            // 8-lane reductions over d-pairs
            #pragma unroll
            for (int msk = 1; msk <= 4; msk <<= 1) {
                llocal += __shfl_xor(llocal, msk, 8);
                c0l    += __shfl_xor(c0l,    msk, 8);
            }
            if (dp == 0) {
                const float lt   = llocal;
                const float cost = S0 * fmaf(16.f, beta_v[oo], lt);
                const float invtemp = 1.0f + (float)sweep;       // 1,2,3
                const float oact = 1.f / (1.f + __expf(-invtemp * (beta_a[oo] - cost)));
                if (sweep < 2)
                    sBias[oo] = __logf(oact + EPSF) - lt - c0l;
                else
                    out[POSE_OUT + (size_t)n * OCAP + oo] = oact;
            }
        }
        __syncthreads();
    }
}

} // namespace

extern "C" void kernel_launch(void* const* d_in, const int* in_sizes, int n_in,
                              void* d_out, int out_size, void* d_ws, size_t ws_size,
                              hipStream_t stream) {
    const float* pose_in = (const float*)d_in[0];
    const float* act_in  = (const float*)d_in[1];
    const float* wmat    = (const float*)d_in[2];
    const float* beta_v  = (const float*)d_in[3];
    const float* beta_a  = (const float*)d_in[4];
    float* out = (float*)d_out;

    caps_em_fused<<<dim3(NPOS), dim3(512), 0, stream>>>(
        pose_in, act_in, wmat, beta_v, beta_a, out);
}